// Round 4
// baseline (25779.150 us; speedup 1.0000x reference)
//
#include <hip/hip_runtime.h>
#include <math.h>

// Problem constants (FrameRNN): B=16, S=8192, T=512, D=1024, 3D=3072, L=4, k=4.
#define T_STEPS 512
#define NPHASE (T_STEPS + 4)
#define NBLK 256

using short8  = __attribute__((ext_vector_type(8))) short;   // 8 bf16 (4 VGPRs)
using floatx4 = __attribute__((ext_vector_type(4))) float;

static __device__ __forceinline__ floatx4 MFMA(short8 a, short8 b, floatx4 c){
  return __builtin_amdgcn_mfma_f32_16x16x32_bf16(a, b, c, 0, 0, 0);
}

// manual RNE f32->bf16
static __device__ __forceinline__ unsigned short f2bf(float f){
  unsigned int u = __builtin_bit_cast(unsigned int, f);
  u += 0x7fffu + ((u >> 16) & 1u);
  return (unsigned short)(u >> 16);
}
static __device__ __forceinline__ float bf2f(unsigned short s){
  unsigned int u = ((unsigned int)s) << 16;
  return __builtin_bit_cast(float, u);
}

// ---------------------------------------------------------------------------
// Persistent-grid barrier: monotonic counter, agent-scope atomics + fences.
// Requires all NBLK blocks co-resident (guaranteed: 106KB LDS -> 1 block/CU,
// grid = 256 = CU count). Failsafe: bounded spin writes sentinel to out[0].
// ---------------------------------------------------------------------------
static __device__ __forceinline__ void gbar(unsigned* cnt, unsigned target, float* out){
  __syncthreads();                      // compiler emits vmcnt(0) drain first
  if (threadIdx.x == 0){
    __threadfence();                    // release (agent scope, xcd L2 wb)
    __hip_atomic_fetch_add(cnt, 1u, __ATOMIC_RELAXED, __HIP_MEMORY_SCOPE_AGENT);
    long spins = 0;
    while (__hip_atomic_load(cnt, __ATOMIC_RELAXED, __HIP_MEMORY_SCOPE_AGENT) < target){
      __builtin_amdgcn_s_sleep(2);
      if (++spins > 20000000L){ out[0] = 1.0e9f; break; }   // deadlock sentinel
    }
    __threadfence();                    // acquire (invalidate L1/L2)
  }
  __syncthreads();
}

// ---------------------------------------------------------------------------
// Pack GRU weights + ConvT weights into MFMA B-fragment order, bf16.
// wpack[l][dt(64)][ks(192)][lane(64)][j(8)]:
//   ks 0..63   : Z  gate, fused K=2048 ([inp;h] vs [Wx;Wh] cols d)
//   ks 64..127 : R  gate, fused K=2048, cols 1024+d
//   ks 128..159: XH (Wx cols 2048+d, K=1024)
//   ks 160..191: HH (Wh cols 2048+d, K=1024)
// B-frag: lane holds B[k = s*32 + (lane>>4)*8 + j][col = tile*16 + (lane&15)]
// ---------------------------------------------------------------------------
__global__ void pack_weights(const float* __restrict__ wx, const float* __restrict__ wh,
                             const float* __restrict__ wup,
                             unsigned short* __restrict__ wpk, unsigned short* __restrict__ wupk){
  const int id = blockIdx.x * 256 + threadIdx.x;
  const int NWP = 4 * 64 * 192 * 64;           // 3,145,728 fragment-threads
  alignas(16) unsigned short o8[8];
  if (id < NWP){
    int lane = id & 63;
    int rest = id >> 6;
    int ks = rest % 192; rest /= 192;
    int dt = rest & 63;
    int l  = rest >> 6;
    const int c = lane & 15, kg = lane >> 4;
    const int d = dt * 16 + c;
    int part, s;
    if (ks < 64)       { part = 0; s = ks; }
    else if (ks < 128) { part = 1; s = ks - 64; }
    else if (ks < 160) { part = 2; s = ks - 128; }
    else               { part = 3; s = ks - 160; }
#pragma unroll
    for (int j = 0; j < 8; ++j){
      int k = s * 32 + kg * 8 + j;
      float v;
      if (part <= 1){
        int col = (part == 0 ? 0 : 1024) + d;
        v = (k < 1024) ? wx[((size_t)l * 1024 + k) * 3072 + col]
                       : wh[((size_t)l * 1024 + (k - 1024)) * 3072 + col];
      } else if (part == 2){
        v = wx[((size_t)l * 1024 + k) * 3072 + 2048 + d];
      } else {
        v = wh[((size_t)l * 1024 + k) * 3072 + 2048 + d];
      }
      o8[j] = f2bf(v);
    }
    *reinterpret_cast<uint4*>(wpk + (size_t)id * 8) = *reinterpret_cast<const uint4*>(o8);
  } else {
    int iu = id - NWP;
    const int NUP = 256 * 32 * 64;             // 524,288
    if (iu < NUP){
      int lane = iu & 63;
      int s  = (iu >> 6) & 31;
      int ct = iu >> 11;
      const int c = lane & 15, kg = lane >> 4;
      int colg = ct * 16 + c;
      int kup = colg >> 10, oc = colg & 1023;
#pragma unroll
      for (int j = 0; j < 8; ++j){
        int k = s * 32 + kg * 8 + j;
        o8[j] = f2bf(wup[((size_t)kup * 1024 + k) * 1024 + oc]);
      }
      *reinterpret_cast<uint4*>(wupk + (size_t)iu * 8) = *reinterpret_cast<const uint4*>(o8);
    }
  }
}

// ---------------------------------------------------------------------------
// x[t][b][d] = frames(b,t)@W_in + b_in + cond   -> bf16
// ---------------------------------------------------------------------------
__global__ void input_proj(const int* __restrict__ qin, const float* __restrict__ cond,
                           const float* __restrict__ win, const float* __restrict__ bin,
                           unsigned short* __restrict__ xb){
  const int id = blockIdx.x * 256 + threadIdx.x;  // 512*16*1024 exact
  const int d = id & 1023;
  const int b = (id >> 10) & 15;
  const int t = id >> 14;
  float acc = bin[d] + cond[((size_t)b * 512 + t) * 1024 + d];
  const int* ip = qin + b * 8192 + t * 16;
#pragma unroll
  for (int f = 0; f < 16; ++f){
    float fv = (float)ip[f] * (1.0f / 64.0f) - 2.0f;   // == (q/128-1)*2, exact
    acc += fv * win[f * 1024 + d];
  }
  xb[((size_t)(t * 16 + b)) * 1024 + d] = f2bf(acc);
}

// ---------------------------------------------------------------------------
// LDS staging of a [16][1024]-bf16 activation panel, XOR-swizzled (G4 fix for
// the 2048B row stride -> 16-way conflict). swizzle: within-row byte ^= (b&7)<<4
// ---------------------------------------------------------------------------
static __device__ __forceinline__ void stage(unsigned short* dst, const unsigned short* __restrict__ src, int tid){
  const uint4* s4 = reinterpret_cast<const uint4*>(src);
#pragma unroll
  for (int i = 0; i < 8; ++i){
    int gi = i * 256 + tid;                 // 2048 16B-chunks
    int b  = gi >> 7;
    int rb = (gi & 127) * 16;
    uint4 v = s4[gi];
    *reinterpret_cast<uint4*>(reinterpret_cast<char*>(dst) + b * 2048 + (rb ^ ((b & 7) << 4))) = v;
  }
}

// A-frag read: lane holds A[row=lane&15][k = k0 + 8*(lane>>4) + j]
static __device__ __forceinline__ short8 afrag(const unsigned short* lds, int lane, int k0){
  const int c = lane & 15, r = lane >> 4;
  const int off = c * 2048 + ((2 * k0 + 16 * r) ^ ((c & 7) << 4));
  return *reinterpret_cast<const short8*>(reinterpret_cast<const char*>(lds) + off);
}

// ---------------------------------------------------------------------------
// Persistent scan. Grid=256 blocks x 256 threads (1 block/CU via 106KB LDS).
// block -> layer = blk>>6, d-tile = blk&63 ; also ConvT col-tile ct = blk.
// Phase p: layer l processes t=p-l ; ConvT processes t=p-4. One barrier/phase.
// ---------------------------------------------------------------------------
__global__ void __launch_bounds__(256, 1)
scan_kernel(const unsigned short* __restrict__ wpk, const unsigned short* __restrict__ wupk,
            const unsigned short* __restrict__ xb, unsigned short* __restrict__ oacc,
            unsigned short* __restrict__ hbuf, float* __restrict__ hm,
            unsigned short* __restrict__ inpb,
            const float* __restrict__ gbx, const float* __restrict__ gbh,
            const float* __restrict__ bup, float* __restrict__ out,
            unsigned* __restrict__ bar){
  __shared__ unsigned short lds_inp[16 * 1024];   // 32 KB each
  __shared__ unsigned short lds_h  [16 * 1024];
  __shared__ unsigned short lds_uA [16 * 1024];
  __shared__ float lds_acc[4][16][16];            // Z,R,XH,HH tiles
  __shared__ float lds_up [4][16][16];            // ConvT k-split partials

  const int tid   = threadIdx.x;
  const int blk   = blockIdx.x;
  const int layer = blk >> 6;
  const int dt    = blk & 63;
  const int wv    = tid >> 6;
  const int lane  = tid & 63;

  const short8* wb = reinterpret_cast<const short8*>(wpk) + (size_t)((layer * 64 + dt) * 192) * 64;
  const short8* ub = reinterpret_cast<const short8*>(wupk) + (size_t)(blk * 32) * 64;

  for (int p = 0; p < NPHASE; ++p){
    const int  t   = p - layer;
    const bool doL = (t >= 0) && (t < T_STEPS);
    const int  tu  = p - 4;
    const bool doU = (tu >= 0);

    // ---- stage activations to LDS ----
    if (doL){
      const unsigned short* isrc = (layer == 0)
          ? (xb + (size_t)t * 16 * 1024)
          : (inpb + (size_t)((layer * 2) + (t & 1)) * 16 * 1024);
      const unsigned short* hsrc = hbuf + (size_t)((layer * 2) + ((t - 1) & 1)) * 16 * 1024;
      stage(lds_inp, isrc, tid);
      stage(lds_h,   hsrc, tid);
    }
    if (doU) stage(lds_uA, oacc + (size_t)tu * 16 * 1024, tid);
    __syncthreads();

    // ---- MFMA: per-wave gate part. wv0=Z(K2048), wv1=R(K2048), wv2=XH, wv3=HH
    if (doL){
      floatx4 za = {0.f,0.f,0.f,0.f}, zb2 = {0.f,0.f,0.f,0.f};
      if (wv < 2){
        const int base = wv * 64;
#pragma unroll
        for (int s = 0; s < 32; ++s){
          short8 a = afrag(lds_inp, lane, 32 * s);
          short8 w = wb[(base + s) * 64 + lane];
          if (s & 1) zb2 = MFMA(a, w, zb2); else za = MFMA(a, w, za);
        }
#pragma unroll
        for (int s = 0; s < 32; ++s){
          short8 a = afrag(lds_h, lane, 32 * s);
          short8 w = wb[(base + 32 + s) * 64 + lane];
          if (s & 1) zb2 = MFMA(a, w, zb2); else za = MFMA(a, w, za);
        }
      } else {
        const int base = (wv == 2) ? 128 : 160;
        const unsigned short* Ab = (wv == 2) ? lds_inp : lds_h;
#pragma unroll
        for (int s = 0; s < 32; ++s){
          short8 a = afrag(Ab, lane, 32 * s);
          short8 w = wb[(base + s) * 64 + lane];
          if (s & 1) zb2 = MFMA(a, w, zb2); else za = MFMA(a, w, za);
        }
      }
      za = za + zb2;
#pragma unroll
      for (int q = 0; q < 4; ++q) lds_acc[wv][(lane >> 4) * 4 + q][lane & 15] = za[q];
    }
    // ---- MFMA: ConvT tile, K split across 4 waves (8 ksteps each) ----
    if (doU){
      floatx4 ua = {0.f,0.f,0.f,0.f};
#pragma unroll
      for (int i = 0; i < 8; ++i){
        int s = wv * 8 + i;
        short8 a = afrag(lds_uA, lane, 32 * s);
        short8 w = ub[s * 64 + lane];
        ua = MFMA(a, w, ua);
      }
#pragma unroll
      for (int q = 0; q < 4; ++q) lds_up[wv][(lane >> 4) * 4 + q][lane & 15] = ua[q];
    }
    __syncthreads();

    // ---- finalize: GRU gating (one (b,d) per thread) ----
    if (doL){
      const int b  = tid >> 4, dl = tid & 15;
      const int d  = dt * 16 + dl;
      const float bz  = gbx[layer * 3072 + d]        + gbh[layer * 3072 + d];
      const float br  = gbx[layer * 3072 + 1024 + d] + gbh[layer * 3072 + 1024 + d];
      const float bxh = gbx[layer * 3072 + 2048 + d];
      const float bhh = gbh[layer * 3072 + 2048 + d];
      const float zz = lds_acc[0][b][dl] + bz;
      const float rr = lds_acc[1][b][dl] + br;
      const float xh = lds_acc[2][b][dl] + bxh;
      const float hh = lds_acc[3][b][dl] + bhh;
      const float zg = 1.0f / (1.0f + expf(-zz));
      const float rg = 1.0f / (1.0f + expf(-rr));
      const float hc = tanhf(xh + rg * hh);
      const size_t hoff = ((size_t)layer * 16 + b) * 1024 + d;
      const float hp = hm[hoff];                       // f32 master state (in-place)
      const float hn = zg * hp + (1.0f - zg) * hc;
      hm[hoff] = hn;
      const unsigned short hb = f2bf(hn);
      hbuf[(size_t)((layer * 2) + (t & 1)) * 16 * 1024 + (size_t)b * 1024 + d] = hb;
      if (layer < 3)
        inpb[(size_t)(((layer + 1) * 2) + (t & 1)) * 16 * 1024 + (size_t)b * 1024 + d] = hb;
      const size_t ooff = ((size_t)t * 16 + b) * 1024 + d;   // skip-sum accumulator (bf16)
      if (layer == 0) oacc[ooff] = hb;
      else            oacc[ooff] = f2bf(bf2f(oacc[ooff]) + hn);
    }
    // ---- finalize: ConvT reduce + store ----
    if (doU){
      const int b = tid >> 4, c = tid & 15;
      const float sum = lds_up[0][b][c] + lds_up[1][b][c] + lds_up[2][b][c] + lds_up[3][b][c];
      const int colg = blk * 16 + c;
      const int kup = colg >> 10, oc = colg & 1023;
      out[((size_t)b * 2048 + (size_t)tu * 4 + kup) * 1024 + oc] = sum + bup[oc];
    }
    gbar(bar, (unsigned)NBLK * (unsigned)(p + 1), out);
  }
}

// ---------------------------------------------------------------------------
extern "C" void kernel_launch(void* const* d_in, const int* in_sizes, int n_in,
                              void* d_out, int out_size, void* d_ws, size_t ws_size,
                              hipStream_t stream){
  char* ws = (char*)d_ws;
  // ws layout (bytes): total ~88.8 MB
  unsigned short* wpk  = (unsigned short*)(ws + 0);          // 50,331,648  packed GRU W (bf16)
  unsigned short* wupk = (unsigned short*)(ws + 50331648);   //  8,388,608  packed ConvT W
  unsigned short* xbuf = (unsigned short*)(ws + 58720256);   // 16,777,216  x[t][b][d] bf16
  unsigned short* oacc = (unsigned short*)(ws + 75497472);   // 16,777,216  skip-sum bf16
  unsigned short* hbuf = (unsigned short*)(ws + 92274688);   //    262,144  h bf16 (parity pair)
  float*          hm   = (float*)        (ws + 92536832);    //    262,144  h f32 master
  unsigned short* inpb = (unsigned short*)(ws + 92798976);   //    262,144  layer-input bf16
  unsigned*       bar  = (unsigned*)     (ws + 93061120);    //          4  grid barrier counter

  const int*   qin  = (const int*)  d_in[0];
  const float* cond = (const float*)d_in[1];
  const float* win  = (const float*)d_in[2];
  const float* bin  = (const float*)d_in[3];
  const float* wx   = (const float*)d_in[4];
  const float* wh   = (const float*)d_in[5];
  const float* gbx  = (const float*)d_in[6];
  const float* gbh  = (const float*)d_in[7];
  const float* wup  = (const float*)d_in[8];
  const float* bup  = (const float*)d_in[9];
  float* out = (float*)d_out;

  // zero h state + rings + barrier counter (ws is poisoned 0xAA before every launch)
  hipMemsetAsync(ws + 92274688, 0, 786496, stream);
  hipLaunchKernelGGL(pack_weights, dim3(14336), dim3(256), 0, stream, wx, wh, wup, wpk, wupk);
  hipLaunchKernelGGL(input_proj,  dim3(32768), dim3(256), 0, stream, qin, cond, win, bin, xbuf);
  hipLaunchKernelGGL(scan_kernel, dim3(NBLK), dim3(256), 0, stream,
                     wpk, wupk, xbuf, oacc, hbuf, hm, inpb, gbx, gbh, bup, out, bar);
}

// Round 5
// 13791.512 us; speedup vs baseline: 1.8692x; 1.8692x over previous
//
#include <hip/hip_runtime.h>
#include <math.h>

// Problem constants (FrameRNN): B=16, S=8192, T=512, D=1024, 3D=3072, L=4, k=4.
#define T_STEPS 512
#define NPHASE (T_STEPS + 4)
#define NBLK 256

using short8  = __attribute__((ext_vector_type(8))) short;   // 8 bf16 (4 VGPRs)
using floatx4 = __attribute__((ext_vector_type(4))) float;

static __device__ __forceinline__ floatx4 MFMA(short8 a, short8 b, floatx4 c){
  return __builtin_amdgcn_mfma_f32_16x16x32_bf16(a, b, c, 0, 0, 0);
}

// manual RNE f32->bf16
static __device__ __forceinline__ unsigned short f2bf(float f){
  unsigned int u = __builtin_bit_cast(unsigned int, f);
  u += 0x7fffu + ((u >> 16) & 1u);
  return (unsigned short)(u >> 16);
}
static __device__ __forceinline__ float bf2f(unsigned short s){
  unsigned int u = ((unsigned int)s) << 16;
  return __builtin_bit_cast(float, u);
}

// ---------------------------------------------------------------------------
// Persistent-grid barrier: monotonic counter, agent-scope atomics + fences.
// NOTE (r4 post-mortem): the agent-scope acquire fence lowers to an L2-wide
// buffer_inv -> all L2s turn over every phase (FETCH 30MB/phase). Weights are
// therefore kept in VGPRs (see scan_kernel); only small activation/comm
// buffers pay the re-fetch.
// ---------------------------------------------------------------------------
static __device__ __forceinline__ void gbar(unsigned* cnt, unsigned target, float* out){
  __syncthreads();                      // compiler emits vmcnt(0) drain first
  if (threadIdx.x == 0){
    __threadfence();                    // release (agent scope, xcd L2 wb)
    __hip_atomic_fetch_add(cnt, 1u, __ATOMIC_RELAXED, __HIP_MEMORY_SCOPE_AGENT);
    long spins = 0;
    while (__hip_atomic_load(cnt, __ATOMIC_RELAXED, __HIP_MEMORY_SCOPE_AGENT) < target){
      __builtin_amdgcn_s_sleep(2);
      if (++spins > 20000000L){ out[0] = 1.0e9f; break; }   // deadlock sentinel
    }
    __threadfence();                    // acquire (invalidate L1/L2)
  }
  __syncthreads();
}

// ---------------------------------------------------------------------------
// Pack GRU weights + ConvT weights into MFMA B-fragment order, bf16.
// wpack[l][dt(64)][ks(192)][lane(64)][j(8)]:
//   ks 0..63   : Z  gate, fused K=2048 ([inp;h] vs [Wx;Wh] cols d)
//   ks 64..127 : R  gate, fused K=2048, cols 1024+d
//   ks 128..159: XH (Wx cols 2048+d, K=1024)
//   ks 160..191: HH (Wh cols 2048+d, K=1024)
// B-frag: lane holds B[k = s*32 + (lane>>4)*8 + j][col = tile*16 + (lane&15)]
// ---------------------------------------------------------------------------
__global__ void pack_weights(const float* __restrict__ wx, const float* __restrict__ wh,
                             const float* __restrict__ wup,
                             unsigned short* __restrict__ wpk, unsigned short* __restrict__ wupk){
  const int id = blockIdx.x * 256 + threadIdx.x;
  const int NWP = 4 * 64 * 192 * 64;           // 3,145,728 fragment-threads
  alignas(16) unsigned short o8[8];
  if (id < NWP){
    int lane = id & 63;
    int rest = id >> 6;
    int ks = rest % 192; rest /= 192;
    int dt = rest & 63;
    int l  = rest >> 6;
    const int c = lane & 15, kg = lane >> 4;
    const int d = dt * 16 + c;
    int part, s;
    if (ks < 64)       { part = 0; s = ks; }
    else if (ks < 128) { part = 1; s = ks - 64; }
    else if (ks < 160) { part = 2; s = ks - 128; }
    else               { part = 3; s = ks - 160; }
#pragma unroll
    for (int j = 0; j < 8; ++j){
      int k = s * 32 + kg * 8 + j;
      float v;
      if (part <= 1){
        int col = (part == 0 ? 0 : 1024) + d;
        v = (k < 1024) ? wx[((size_t)l * 1024 + k) * 3072 + col]
                       : wh[((size_t)l * 1024 + (k - 1024)) * 3072 + col];
      } else if (part == 2){
        v = wx[((size_t)l * 1024 + k) * 3072 + 2048 + d];
      } else {
        v = wh[((size_t)l * 1024 + k) * 3072 + 2048 + d];
      }
      o8[j] = f2bf(v);
    }
    *reinterpret_cast<uint4*>(wpk + (size_t)id * 8) = *reinterpret_cast<const uint4*>(o8);
  } else {
    int iu = id - NWP;
    const int NUP = 256 * 32 * 64;             // 524,288
    if (iu < NUP){
      int lane = iu & 63;
      int s  = (iu >> 6) & 31;
      int ct = iu >> 11;
      const int c = lane & 15, kg = lane >> 4;
      int colg = ct * 16 + c;
      int kup = colg >> 10, oc = colg & 1023;
#pragma unroll
      for (int j = 0; j < 8; ++j){
        int k = s * 32 + kg * 8 + j;
        o8[j] = f2bf(wup[((size_t)kup * 1024 + k) * 1024 + oc]);
      }
      *reinterpret_cast<uint4*>(wupk + (size_t)iu * 8) = *reinterpret_cast<const uint4*>(o8);
    }
  }
}

// ---------------------------------------------------------------------------
// x[t][b][d] = frames(b,t)@W_in + b_in + cond   -> bf16
// ---------------------------------------------------------------------------
__global__ void input_proj(const int* __restrict__ qin, const float* __restrict__ cond,
                           const float* __restrict__ win, const float* __restrict__ bin,
                           unsigned short* __restrict__ xb){
  const int id = blockIdx.x * 256 + threadIdx.x;  // 512*16*1024 exact
  const int d = id & 1023;
  const int b = (id >> 10) & 15;
  const int t = id >> 14;
  float acc = bin[d] + cond[((size_t)b * 512 + t) * 1024 + d];
  const int* ip = qin + b * 8192 + t * 16;
#pragma unroll
  for (int f = 0; f < 16; ++f){
    float fv = (float)ip[f] * (1.0f / 64.0f) - 2.0f;   // == (q/128-1)*2, exact
    acc += fv * win[f * 1024 + d];
  }
  xb[((size_t)(t * 16 + b)) * 1024 + d] = f2bf(acc);
}

// ---------------------------------------------------------------------------
// LDS staging of a [16][1024]-bf16 activation panel, XOR-swizzled (G4 fix for
// the 2048B row stride -> 16-way conflict). swizzle: within-row byte ^= (b&7)<<4
// ---------------------------------------------------------------------------
static __device__ __forceinline__ void stage(unsigned short* dst, const unsigned short* __restrict__ src, int tid){
  const uint4* s4 = reinterpret_cast<const uint4*>(src);
#pragma unroll
  for (int i = 0; i < 8; ++i){
    int gi = i * 256 + tid;                 // 2048 16B-chunks
    int b  = gi >> 7;
    int rb = (gi & 127) * 16;
    uint4 v = s4[gi];
    *reinterpret_cast<uint4*>(reinterpret_cast<char*>(dst) + b * 2048 + (rb ^ ((b & 7) << 4))) = v;
  }
}

// A-frag read: lane holds A[row=lane&15][k = k0 + 8*(lane>>4) + j]
static __device__ __forceinline__ short8 afrag(const unsigned short* lds, int lane, int k0){
  const int c = lane & 15, r = lane >> 4;
  const int off = c * 2048 + ((2 * k0 + 16 * r) ^ ((c & 7) << 4));
  return *reinterpret_cast<const short8*>(reinterpret_cast<const char*>(lds) + off);
}

// ---------------------------------------------------------------------------
// Persistent scan. Grid=256 blocks x 256 threads (1 block/CU via 106KB LDS).
// block -> layer = blk>>6, d-tile = blk&63 ; also ConvT col-tile ct = blk.
// Phase p: layer l processes t=p-l ; ConvT processes t=p-4. One barrier/phase.
// r5: weights preloaded into VGPRs (<=256+32 regs/lane) so the per-phase L2
// invalidate (gbar fence) has no 50MB weight set to re-fetch.
// ---------------------------------------------------------------------------
__global__ void __launch_bounds__(256, 1)
scan_kernel(const unsigned short* __restrict__ wpk, const unsigned short* __restrict__ wupk,
            const unsigned short* __restrict__ xb, unsigned short* __restrict__ oacc,
            unsigned short* __restrict__ hbuf, float* __restrict__ hm,
            unsigned short* __restrict__ inpb,
            const float* __restrict__ gbx, const float* __restrict__ gbh,
            const float* __restrict__ bup, float* __restrict__ out,
            unsigned* __restrict__ bar){
  __shared__ unsigned short lds_inp[16 * 1024];   // 32 KB each
  __shared__ unsigned short lds_h  [16 * 1024];
  __shared__ unsigned short lds_uA [16 * 1024];
  __shared__ float lds_acc[4][16][16];            // Z,R,XH,HH tiles
  __shared__ float lds_up [4][16][16];            // ConvT k-split partials

  const int tid   = threadIdx.x;
  const int blk   = blockIdx.x;
  const int layer = blk >> 6;
  const int dt    = blk & 63;
  const int wv    = tid >> 6;
  const int lane  = tid & 63;

  const short8* wb = reinterpret_cast<const short8*>(wpk) + (size_t)((layer * 64 + dt) * 192) * 64;
  const short8* ub = reinterpret_cast<const short8*>(wupk) + (size_t)(blk * 32) * 64;

  // ---- preload this wave's weight slice into registers (static indices only)
  // wv0: Z ks 0..63 ; wv1: R ks 64..127 ; wv2: XH ks 128..159 ; wv3: HH ks 160..191
  short8 wr[64];
  short8 ur[8];
  {
    const int kbase = (wv == 0) ? 0 : (wv == 1) ? 64 : (wv == 2) ? 128 : 160;
#pragma unroll
    for (int s = 0; s < 32; ++s) wr[s] = wb[(kbase + s) * 64 + lane];
    if (wv < 2){                                   // wave-uniform branch
#pragma unroll
      for (int s = 0; s < 32; ++s) wr[32 + s] = wb[(kbase + 32 + s) * 64 + lane];
    }
#pragma unroll
    for (int i = 0; i < 8; ++i) ur[i] = ub[(wv * 8 + i) * 64 + lane];
  }

  for (int p = 0; p < NPHASE; ++p){
    const int  t   = p - layer;
    const bool doL = (t >= 0) && (t < T_STEPS);
    const int  tu  = p - 4;
    const bool doU = (tu >= 0);

    // ---- stage activations to LDS ----
    if (doL){
      const unsigned short* isrc = (layer == 0)
          ? (xb + (size_t)t * 16 * 1024)
          : (inpb + (size_t)((layer * 2) + (t & 1)) * 16 * 1024);
      const unsigned short* hsrc = hbuf + (size_t)((layer * 2) + ((t - 1) & 1)) * 16 * 1024;
      stage(lds_inp, isrc, tid);
      stage(lds_h,   hsrc, tid);
    }
    if (doU) stage(lds_uA, oacc + (size_t)tu * 16 * 1024, tid);
    __syncthreads();

    // ---- MFMA: per-wave gate part. wv0=Z(K2048), wv1=R(K2048), wv2=XH, wv3=HH
    if (doL){
      floatx4 za = {0.f,0.f,0.f,0.f}, zb2 = {0.f,0.f,0.f,0.f};
      if (wv < 2){
#pragma unroll
        for (int s = 0; s < 32; ++s){
          short8 a = afrag(lds_inp, lane, 32 * s);
          if (s & 1) zb2 = MFMA(a, wr[s], zb2); else za = MFMA(a, wr[s], za);
        }
#pragma unroll
        for (int s = 0; s < 32; ++s){
          short8 a = afrag(lds_h, lane, 32 * s);
          if (s & 1) zb2 = MFMA(a, wr[32 + s], zb2); else za = MFMA(a, wr[32 + s], za);
        }
      } else {
        const unsigned short* Ab = (wv == 2) ? lds_inp : lds_h;
#pragma unroll
        for (int s = 0; s < 32; ++s){
          short8 a = afrag(Ab, lane, 32 * s);
          if (s & 1) zb2 = MFMA(a, wr[s], zb2); else za = MFMA(a, wr[s], za);
        }
      }
      za = za + zb2;
#pragma unroll
      for (int q = 0; q < 4; ++q) lds_acc[wv][(lane >> 4) * 4 + q][lane & 15] = za[q];
    }
    // ---- MFMA: ConvT tile, K split across 4 waves (8 ksteps each) ----
    if (doU){
      floatx4 ua = {0.f,0.f,0.f,0.f};
#pragma unroll
      for (int i = 0; i < 8; ++i){
        short8 a = afrag(lds_uA, lane, 32 * (wv * 8 + i));
        ua = MFMA(a, ur[i], ua);
      }
#pragma unroll
      for (int q = 0; q < 4; ++q) lds_up[wv][(lane >> 4) * 4 + q][lane & 15] = ua[q];
    }
    __syncthreads();

    // ---- finalize: GRU gating (one (b,d) per thread) ----
    if (doL){
      const int b  = tid >> 4, dl = tid & 15;
      const int d  = dt * 16 + dl;
      const float bz  = gbx[layer * 3072 + d]        + gbh[layer * 3072 + d];
      const float br  = gbx[layer * 3072 + 1024 + d] + gbh[layer * 3072 + 1024 + d];
      const float bxh = gbx[layer * 3072 + 2048 + d];
      const float bhh = gbh[layer * 3072 + 2048 + d];
      const float zz = lds_acc[0][b][dl] + bz;
      const float rr = lds_acc[1][b][dl] + br;
      const float xh = lds_acc[2][b][dl] + bxh;
      const float hh = lds_acc[3][b][dl] + bhh;
      const float zg = 1.0f / (1.0f + expf(-zz));
      const float rg = 1.0f / (1.0f + expf(-rr));
      const float hc = tanhf(xh + rg * hh);
      const size_t hoff = ((size_t)layer * 16 + b) * 1024 + d;
      const float hp = hm[hoff];                       // f32 master state (in-place)
      const float hn = zg * hp + (1.0f - zg) * hc;
      hm[hoff] = hn;
      const unsigned short hb = f2bf(hn);
      hbuf[(size_t)((layer * 2) + (t & 1)) * 16 * 1024 + (size_t)b * 1024 + d] = hb;
      if (layer < 3)
        inpb[(size_t)(((layer + 1) * 2) + (t & 1)) * 16 * 1024 + (size_t)b * 1024 + d] = hb;
      const size_t ooff = ((size_t)t * 16 + b) * 1024 + d;   // skip-sum accumulator (bf16)
      if (layer == 0) oacc[ooff] = hb;
      else            oacc[ooff] = f2bf(bf2f(oacc[ooff]) + hn);
    }
    // ---- finalize: ConvT reduce + store ----
    if (doU){
      const int b = tid >> 4, c = tid & 15;
      const float sum = lds_up[0][b][c] + lds_up[1][b][c] + lds_up[2][b][c] + lds_up[3][b][c];
      const int colg = blk * 16 + c;
      const int kup = colg >> 10, oc = colg & 1023;
      out[((size_t)b * 2048 + (size_t)tu * 4 + kup) * 1024 + oc] = sum + bup[oc];
    }
    gbar(bar, (unsigned)NBLK * (unsigned)(p + 1), out);
  }
}

// ---------------------------------------------------------------------------
extern "C" void kernel_launch(void* const* d_in, const int* in_sizes, int n_in,
                              void* d_out, int out_size, void* d_ws, size_t ws_size,
                              hipStream_t stream){
  char* ws = (char*)d_ws;
  // ws layout (bytes): total ~88.8 MB
  unsigned short* wpk  = (unsigned short*)(ws + 0);          // 50,331,648  packed GRU W (bf16)
  unsigned short* wupk = (unsigned short*)(ws + 50331648);   //  8,388,608  packed ConvT W
  unsigned short* xbuf = (unsigned short*)(ws + 58720256);   // 16,777,216  x[t][b][d] bf16
  unsigned short* oacc = (unsigned short*)(ws + 75497472);   // 16,777,216  skip-sum bf16
  unsigned short* hbuf = (unsigned short*)(ws + 92274688);   //    262,144  h bf16 (parity pair)
  float*          hm   = (float*)        (ws + 92536832);    //    262,144  h f32 master
  unsigned short* inpb = (unsigned short*)(ws + 92798976);   //    262,144  layer-input bf16
  unsigned*       bar  = (unsigned*)     (ws + 93061120);    //          4  grid barrier counter

  const int*   qin  = (const int*)  d_in[0];
  const float* cond = (const float*)d_in[1];
  const float* win  = (const float*)d_in[2];
  const float* bin  = (const float*)d_in[3];
  const float* wx   = (const float*)d_in[4];
  const float* wh   = (const float*)d_in[5];
  const float* gbx  = (const float*)d_in[6];
  const float* gbh  = (const float*)d_in[7];
  const float* wup  = (const float*)d_in[8];
  const float* bup  = (const float*)d_in[9];
  float* out = (float*)d_out;

  // zero h state + rings + barrier counter (ws is poisoned 0xAA before every launch)
  hipMemsetAsync(ws + 92274688, 0, 786496, stream);
  hipLaunchKernelGGL(pack_weights, dim3(14336), dim3(256), 0, stream, wx, wh, wup, wpk, wupk);
  hipLaunchKernelGGL(input_proj,  dim3(32768), dim3(256), 0, stream, qin, cond, win, bin, xbuf);
  hipLaunchKernelGGL(scan_kernel, dim3(NBLK), dim3(256), 0, stream,
                     wpk, wupk, xbuf, oacc, hbuf, hm, inpb, gbx, gbh, bup, out, bar);
}

// Round 6
// 10783.987 us; speedup vs baseline: 2.3905x; 1.2789x over previous
//
#include <hip/hip_runtime.h>
#include <math.h>

// Problem constants (FrameRNN): B=16, S=8192, T=512, D=1024, 3D=3072, L=4, k=4.
#define T_STEPS 512
#define NPHASE (T_STEPS + 4)
#define NBLK 256

using short8  = __attribute__((ext_vector_type(8))) short;   // 8 bf16 (4 VGPRs)
using floatx4 = __attribute__((ext_vector_type(4))) float;

static __device__ __forceinline__ floatx4 MFMA(short8 a, short8 b, floatx4 c){
  return __builtin_amdgcn_mfma_f32_16x16x32_bf16(a, b, c, 0, 0, 0);
}

// manual RNE f32->bf16
static __device__ __forceinline__ unsigned short f2bf(float f){
  unsigned int u = __builtin_bit_cast(unsigned int, f);
  u += 0x7fffu + ((u >> 16) & 1u);
  return (unsigned short)(u >> 16);
}
static __device__ __forceinline__ float bf2f(unsigned short s){
  unsigned int u = ((unsigned int)s) << 16;
  return __builtin_bit_cast(float, u);
}

// ---------------------------------------------------------------------------
// Tree barrier v2 (r6): r5's single counter = 256 same-line atomic RMWs,
// serialized at the coherence point (~50-100ns each ~= 13-25us/phase).
// Now: per-block flag lines (64B stride, contention-free fetch_add) ->
// block 0's 256 threads poll all flags in parallel -> one epoch line release.
// Same proven primitives as r4/r5 (agent-scope add + load polling).
// ---------------------------------------------------------------------------
static __device__ __forceinline__ void gbar2(unsigned* flags, unsigned* epoch,
                                             unsigned p1, float* out, int blk, int tid){
  __syncthreads();                      // all 4 waves drain vmcnt before fence
  if (blk == 0){
    if (tid == 0){
      __threadfence();                  // release: publish this block's stores
      __hip_atomic_fetch_add(&flags[0], 1u, __ATOMIC_RELAXED, __HIP_MEMORY_SCOPE_AGENT);
    }
    long spins = 0;                     // thread tid polls block tid's flag
    while (__hip_atomic_load(&flags[(unsigned)tid * 16u], __ATOMIC_RELAXED,
                             __HIP_MEMORY_SCOPE_AGENT) < p1){
      __builtin_amdgcn_s_sleep(1);
      if (++spins > 20000000L){ out[0] = 1.0e9f; break; }   // deadlock sentinel
    }
    __syncthreads();                    // all 256 flags seen
    if (tid == 0)
      __hip_atomic_fetch_add(epoch, 1u, __ATOMIC_RELAXED, __HIP_MEMORY_SCOPE_AGENT);
  } else {
    if (tid == 0){
      __threadfence();                  // release: publish this block's stores
      __hip_atomic_fetch_add(&flags[(unsigned)blk * 16u], 1u, __ATOMIC_RELAXED,
                             __HIP_MEMORY_SCOPE_AGENT);
    }
  }
  if (tid == 0){
    long spins = 0;
    while (__hip_atomic_load(epoch, __ATOMIC_RELAXED, __HIP_MEMORY_SCOPE_AGENT) < p1){
      __builtin_amdgcn_s_sleep(1);
      if (++spins > 20000000L){ out[0] = 1.0e9f; break; }
    }
    __threadfence();                    // acquire: invalidate stale L1/L2
  }
  __syncthreads();
}

// ---------------------------------------------------------------------------
// Pack GRU weights + ConvT weights into MFMA B-fragment order, bf16.
// wpack[l][dt(64)][ks(192)][lane(64)][j(8)]:
//   ks 0..63   : Z  gate, fused K=2048 ([inp;h] vs [Wx;Wh] cols d)
//   ks 64..127 : R  gate, fused K=2048, cols 1024+d
//   ks 128..159: XH (Wx cols 2048+d, K=1024)
//   ks 160..191: HH (Wh cols 2048+d, K=1024)
// B-frag: lane holds B[k = s*32 + (lane>>4)*8 + j][col = tile*16 + (lane&15)]
// ---------------------------------------------------------------------------
__global__ void pack_weights(const float* __restrict__ wx, const float* __restrict__ wh,
                             const float* __restrict__ wup,
                             unsigned short* __restrict__ wpk, unsigned short* __restrict__ wupk){
  const int id = blockIdx.x * 256 + threadIdx.x;
  const int NWP = 4 * 64 * 192 * 64;           // 3,145,728 fragment-threads
  alignas(16) unsigned short o8[8];
  if (id < NWP){
    int lane = id & 63;
    int rest = id >> 6;
    int ks = rest % 192; rest /= 192;
    int dt = rest & 63;
    int l  = rest >> 6;
    const int c = lane & 15, kg = lane >> 4;
    const int d = dt * 16 + c;
    int part, s;
    if (ks < 64)       { part = 0; s = ks; }
    else if (ks < 128) { part = 1; s = ks - 64; }
    else if (ks < 160) { part = 2; s = ks - 128; }
    else               { part = 3; s = ks - 160; }
#pragma unroll
    for (int j = 0; j < 8; ++j){
      int k = s * 32 + kg * 8 + j;
      float v;
      if (part <= 1){
        int col = (part == 0 ? 0 : 1024) + d;
        v = (k < 1024) ? wx[((size_t)l * 1024 + k) * 3072 + col]
                       : wh[((size_t)l * 1024 + (k - 1024)) * 3072 + col];
      } else if (part == 2){
        v = wx[((size_t)l * 1024 + k) * 3072 + 2048 + d];
      } else {
        v = wh[((size_t)l * 1024 + k) * 3072 + 2048 + d];
      }
      o8[j] = f2bf(v);
    }
    *reinterpret_cast<uint4*>(wpk + (size_t)id * 8) = *reinterpret_cast<const uint4*>(o8);
  } else {
    int iu = id - NWP;
    const int NUP = 256 * 32 * 64;             // 524,288
    if (iu < NUP){
      int lane = iu & 63;
      int s  = (iu >> 6) & 31;
      int ct = iu >> 11;
      const int c = lane & 15, kg = lane >> 4;
      int colg = ct * 16 + c;
      int kup = colg >> 10, oc = colg & 1023;
#pragma unroll
      for (int j = 0; j < 8; ++j){
        int k = s * 32 + kg * 8 + j;
        o8[j] = f2bf(wup[((size_t)kup * 1024 + k) * 1024 + oc]);
      }
      *reinterpret_cast<uint4*>(wupk + (size_t)iu * 8) = *reinterpret_cast<const uint4*>(o8);
    }
  }
}

// ---------------------------------------------------------------------------
// x[t][b][d] = frames(b,t)@W_in + b_in + cond   -> bf16
// ---------------------------------------------------------------------------
__global__ void input_proj(const int* __restrict__ qin, const float* __restrict__ cond,
                           const float* __restrict__ win, const float* __restrict__ bin,
                           unsigned short* __restrict__ xb){
  const int id = blockIdx.x * 256 + threadIdx.x;  // 512*16*1024 exact
  const int d = id & 1023;
  const int b = (id >> 10) & 15;
  const int t = id >> 14;
  float acc = bin[d] + cond[((size_t)b * 512 + t) * 1024 + d];
  const int* ip = qin + b * 8192 + t * 16;
#pragma unroll
  for (int f = 0; f < 16; ++f){
    float fv = (float)ip[f] * (1.0f / 64.0f) - 2.0f;   // == (q/128-1)*2, exact
    acc += fv * win[f * 1024 + d];
  }
  xb[((size_t)(t * 16 + b)) * 1024 + d] = f2bf(acc);
}

// ---------------------------------------------------------------------------
// LDS staging of a [16][1024]-bf16 activation panel, XOR-swizzled (G4 fix for
// the 2048B row stride -> 16-way conflict). swizzle: within-row byte ^= (b&7)<<4
// ---------------------------------------------------------------------------
static __device__ __forceinline__ void stage(unsigned short* dst, const unsigned short* __restrict__ src, int tid){
  const uint4* s4 = reinterpret_cast<const uint4*>(src);
#pragma unroll
  for (int i = 0; i < 8; ++i){
    int gi = i * 256 + tid;                 // 2048 16B-chunks
    int b  = gi >> 7;
    int rb = (gi & 127) * 16;
    uint4 v = s4[gi];
    *reinterpret_cast<uint4*>(reinterpret_cast<char*>(dst) + b * 2048 + (rb ^ ((b & 7) << 4))) = v;
  }
}

// A-frag read: lane holds A[row=lane&15][k = k0 + 8*(lane>>4) + j]
static __device__ __forceinline__ short8 afrag(const unsigned short* lds, int lane, int k0){
  const int c = lane & 15, r = lane >> 4;
  const int off = c * 2048 + ((2 * k0 + 16 * r) ^ ((c & 7) << 4));
  return *reinterpret_cast<const short8*>(reinterpret_cast<const char*>(lds) + off);
}

// ---------------------------------------------------------------------------
// Persistent scan. Grid=256 blocks x 256 threads (1 block/CU via 106KB LDS).
// block -> layer = blk>>6, d-tile = blk&63 ; also ConvT col-tile ct = blk.
// Phase p: layer l processes t=p-l ; ConvT processes t=p-4. One barrier/phase.
// r5: weights preloaded into VGPRs. r6: tree barrier, h-state in registers,
// biases hoisted out of the fenced loop.
// ---------------------------------------------------------------------------
__global__ void __launch_bounds__(256, 1)
scan_kernel(const unsigned short* __restrict__ wpk, const unsigned short* __restrict__ wupk,
            const unsigned short* __restrict__ xb, unsigned short* __restrict__ oacc,
            unsigned short* __restrict__ hbuf, unsigned short* __restrict__ inpb,
            const float* __restrict__ gbx, const float* __restrict__ gbh,
            const float* __restrict__ bup, float* __restrict__ out,
            unsigned* __restrict__ flags, unsigned* __restrict__ epoch){
  __shared__ unsigned short lds_inp[16 * 1024];   // 32 KB each
  __shared__ unsigned short lds_h  [16 * 1024];
  __shared__ unsigned short lds_uA [16 * 1024];
  __shared__ float lds_acc[4][16][16];            // Z,R,XH,HH tiles
  __shared__ float lds_up [4][16][16];            // ConvT k-split partials

  const int tid   = threadIdx.x;
  const int blk   = blockIdx.x;
  const int layer = blk >> 6;
  const int dt    = blk & 63;
  const int wv    = tid >> 6;
  const int lane  = tid & 63;

  const short8* wb = reinterpret_cast<const short8*>(wpk) + (size_t)((layer * 64 + dt) * 192) * 64;
  const short8* ub = reinterpret_cast<const short8*>(wupk) + (size_t)(blk * 32) * 64;

  // ---- preload this wave's weight slice into registers (static indices only)
  // wv0: Z ks 0..63 ; wv1: R ks 64..127 ; wv2: XH ks 128..159 ; wv3: HH ks 160..191
  short8 wr[64];
  short8 ur[8];
  {
    const int kbase = (wv == 0) ? 0 : (wv == 1) ? 64 : (wv == 2) ? 128 : 160;
#pragma unroll
    for (int s = 0; s < 32; ++s) wr[s] = wb[(kbase + s) * 64 + lane];
    if (wv < 2){                                   // wave-uniform branch
#pragma unroll
      for (int s = 0; s < 32; ++s) wr[32 + s] = wb[(kbase + 32 + s) * 64 + lane];
    }
#pragma unroll
    for (int i = 0; i < 8; ++i) ur[i] = ub[(wv * 8 + i) * 64 + lane];
  }

  // ---- hoisted per-thread finalize constants (fence clobber blocks compiler
  //      hoisting; these were 5 L3-latency loads/phase on the critical path)
  const int fb = tid >> 4, fdl = tid & 15;
  const int fd = dt * 16 + fdl;
  const float bz  = gbx[layer * 3072 + fd]        + gbh[layer * 3072 + fd];
  const float br  = gbx[layer * 3072 + 1024 + fd] + gbh[layer * 3072 + 1024 + fd];
  const float bxh = gbx[layer * 3072 + 2048 + fd];
  const float bhh = gbh[layer * 3072 + 2048 + fd];
  const int   colg = blk * 16 + fdl;
  const int   kup  = colg >> 10, oc = colg & 1023;
  const float bupv = bup[oc];
  float hreg = 0.0f;                    // f32 master h state, register-resident

  for (int p = 0; p < NPHASE; ++p){
    const int  t   = p - layer;
    const bool doL = (t >= 0) && (t < T_STEPS);
    const int  tu  = p - 4;
    const bool doU = (tu >= 0);

    // ---- stage activations to LDS ----
    if (doL){
      const unsigned short* isrc = (layer == 0)
          ? (xb + (size_t)t * 16 * 1024)
          : (inpb + (size_t)((layer * 2) + (t & 1)) * 16 * 1024);
      const unsigned short* hsrc = hbuf + (size_t)((layer * 2) + ((t - 1) & 1)) * 16 * 1024;
      stage(lds_inp, isrc, tid);
      stage(lds_h,   hsrc, tid);
    }
    if (doU) stage(lds_uA, oacc + (size_t)tu * 16 * 1024, tid);
    __syncthreads();

    // ---- MFMA: per-wave gate part. wv0=Z(K2048), wv1=R(K2048), wv2=XH, wv3=HH
    if (doL){
      floatx4 za = {0.f,0.f,0.f,0.f}, zb2 = {0.f,0.f,0.f,0.f};
      if (wv < 2){
#pragma unroll
        for (int s = 0; s < 32; ++s){
          short8 a = afrag(lds_inp, lane, 32 * s);
          if (s & 1) zb2 = MFMA(a, wr[s], zb2); else za = MFMA(a, wr[s], za);
        }
#pragma unroll
        for (int s = 0; s < 32; ++s){
          short8 a = afrag(lds_h, lane, 32 * s);
          if (s & 1) zb2 = MFMA(a, wr[32 + s], zb2); else za = MFMA(a, wr[32 + s], za);
        }
      } else {
        const unsigned short* Ab = (wv == 2) ? lds_inp : lds_h;
#pragma unroll
        for (int s = 0; s < 32; ++s){
          short8 a = afrag(Ab, lane, 32 * s);
          if (s & 1) zb2 = MFMA(a, wr[s], zb2); else za = MFMA(a, wr[s], za);
        }
      }
      za = za + zb2;
#pragma unroll
      for (int q = 0; q < 4; ++q) lds_acc[wv][(lane >> 4) * 4 + q][lane & 15] = za[q];
    }
    // ---- MFMA: ConvT tile, K split across 4 waves (8 ksteps each) ----
    if (doU){
      floatx4 ua = {0.f,0.f,0.f,0.f};
#pragma unroll
      for (int i = 0; i < 8; ++i){
        short8 a = afrag(lds_uA, lane, 32 * (wv * 8 + i));
        ua = MFMA(a, ur[i], ua);
      }
#pragma unroll
      for (int q = 0; q < 4; ++q) lds_up[wv][(lane >> 4) * 4 + q][lane & 15] = ua[q];
    }
    __syncthreads();

    // ---- finalize: GRU gating (one (b,d) per thread) ----
    if (doL){
      const float zz = lds_acc[0][fb][fdl] + bz;
      const float rr = lds_acc[1][fb][fdl] + br;
      const float xh = lds_acc[2][fb][fdl] + bxh;
      const float hh = lds_acc[3][fb][fdl] + bhh;
      const float zg = 1.0f / (1.0f + expf(-zz));
      const float rg = 1.0f / (1.0f + expf(-rr));
      const float hc = tanhf(xh + rg * hh);
      const float hn = zg * hreg + (1.0f - zg) * hc;
      hreg = hn;
      const unsigned short hb = f2bf(hn);
      hbuf[(size_t)((layer * 2) + (t & 1)) * 16 * 1024 + (size_t)fb * 1024 + fd] = hb;
      if (layer < 3)
        inpb[(size_t)(((layer + 1) * 2) + (t & 1)) * 16 * 1024 + (size_t)fb * 1024 + fd] = hb;
      const size_t ooff = ((size_t)t * 16 + fb) * 1024 + fd;   // skip-sum accumulator (bf16)
      if (layer == 0) oacc[ooff] = hb;
      else            oacc[ooff] = f2bf(bf2f(oacc[ooff]) + hn);
    }
    // ---- finalize: ConvT reduce + store ----
    if (doU){
      const float sum = lds_up[0][fb][fdl] + lds_up[1][fb][fdl]
                      + lds_up[2][fb][fdl] + lds_up[3][fb][fdl];
      out[((size_t)fb * 2048 + (size_t)tu * 4 + kup) * 1024 + oc] = sum + bupv;
    }
    gbar2(flags, epoch, (unsigned)(p + 1), out, blk, tid);
  }
}

// ---------------------------------------------------------------------------
extern "C" void kernel_launch(void* const* d_in, const int* in_sizes, int n_in,
                              void* d_out, int out_size, void* d_ws, size_t ws_size,
                              hipStream_t stream){
  char* ws = (char*)d_ws;
  // ws layout (bytes): total ~92.8 MB
  unsigned short* wpk  = (unsigned short*)(ws + 0);          // 50,331,648  packed GRU W (bf16)
  unsigned short* wupk = (unsigned short*)(ws + 50331648);   //  8,388,608  packed ConvT W
  unsigned short* xbuf = (unsigned short*)(ws + 58720256);   // 16,777,216  x[t][b][d] bf16
  unsigned short* oacc = (unsigned short*)(ws + 75497472);   // 16,777,216  skip-sum bf16
  unsigned short* hbuf = (unsigned short*)(ws + 92274688);   //    262,144  h bf16 (parity pair)
  unsigned short* inpb = (unsigned short*)(ws + 92536832);   //    262,144  layer-input bf16
  unsigned*       flags= (unsigned*)     (ws + 92798976);    //     16,384  per-block arrival flags
  unsigned*       epoch= (unsigned*)     (ws + 92815360);    //         64  release epoch line

  const int*   qin  = (const int*)  d_in[0];
  const float* cond = (const float*)d_in[1];
  const float* win  = (const float*)d_in[2];
  const float* bin  = (const float*)d_in[3];
  const float* wx   = (const float*)d_in[4];
  const float* wh   = (const float*)d_in[5];
  const float* gbx  = (const float*)d_in[6];
  const float* gbh  = (const float*)d_in[7];
  const float* wup  = (const float*)d_in[8];
  const float* bup  = (const float*)d_in[9];
  float* out = (float*)d_out;

  // zero h rings + inp rings + flags + epoch (ws is poisoned 0xAA each launch)
  hipMemsetAsync(ws + 92274688, 0, 540736, stream);
  hipLaunchKernelGGL(pack_weights, dim3(14336), dim3(256), 0, stream, wx, wh, wup, wpk, wupk);
  hipLaunchKernelGGL(input_proj,  dim3(32768), dim3(256), 0, stream, qin, cond, win, bin, xbuf);
  hipLaunchKernelGGL(scan_kernel, dim3(NBLK), dim3(256), 0, stream,
                     wpk, wupk, xbuf, oacc, hbuf, inpb, gbx, gbh, bup, out, flags, epoch);
}